// Round 3
// baseline (247.937 us; speedup 1.0000x reference)
//
#include <hip/hip_runtime.h>
#include <hip/hip_bf16.h>
#include <math.h>

typedef _Float16 half8 __attribute__((ext_vector_type(8)));
typedef float    floatx4 __attribute__((ext_vector_type(4)));

#define IN_CH 64
#define HID   128
#define NSEG  4096

__device__ __forceinline__ unsigned fkey(float s) {
    unsigned u = __float_as_uint(s);
    return (u & 0x80000000u) ? ~u : (u | 0x80000000u);
}
__device__ __forceinline__ float funkey(unsigned k) {
    unsigned u = (k & 0x80000000u) ? (k ^ 0x80000000u) : ~k;
    return __uint_as_float(u);
}

// ---------------- init segment scratch ----------------
__global__ void init_seg(unsigned* __restrict__ segkey, float* __restrict__ denom) {
    int i = blockIdx.x * blockDim.x + threadIdx.x;
    if (i < NSEG) { segkey[i] = 0u; denom[i] = 0.0f; }
}

// ---------------- fused MLP -> scores ----------------
// score[e] = relu(x[e,:] @ w1 + b1) @ w2 + b2   via fp16 MFMA (fp32 accum)
// 16 edges/wave/iter; w1 hoisted in 64 VGPRs; A-tile loads software-pipelined
// one iteration ahead (reg double-buffer) so HBM latency hides under compute.
__global__ __launch_bounds__(256, 3) void mlp_score(
    const float* __restrict__ x, const float* __restrict__ w1,
    const float* __restrict__ b1, const float* __restrict__ w2,
    const float* __restrict__ b2, float* __restrict__ score, int E)
{
    // w1^T as f16 in LDS: row n (hidden col), 64 k-elements (128B), XOR-swizzled
    __shared__ unsigned char w1s[HID * 128];

    const int tid = threadIdx.x;
    for (int i = tid; i < IN_CH * HID; i += 256) {
        int k = i >> 7;        // 0..63
        int n = i & 127;       // 0..127
        unsigned byteoff = (unsigned)(n * 128) + (((unsigned)(k * 2)) ^ ((unsigned)(n & 7) << 4));
        *(_Float16*)(w1s + byteoff) = (_Float16)w1[i];
    }

    const int lane = tid & 63;
    const int wid  = tid >> 6;
    const int g    = lane >> 4;   // 0..3
    const int l15  = lane & 15;   // 0..15

    float b1v[8], w2v[8];
#pragma unroll
    for (int t = 0; t < 8; ++t) {
        b1v[t] = b1[t * 16 + l15];
        w2v[t] = w2[t * 16 + l15];
    }
    const float b2v = b2[0];

    __syncthreads();

    // hoist all 16 B fragments (the weights) into registers once
    half8 bfr[2][8];
#pragma unroll
    for (int ks = 0; ks < 2; ++ks)
#pragma unroll
        for (int ct = 0; ct < 8; ++ct) {
            unsigned boff = (unsigned)((ct * 16 + l15) * 128)
                          + (((unsigned)(ks * 64 + g * 16)) ^ ((unsigned)(l15 & 7) << 4));
            bfr[ks][ct] = *(const half8*)(w1s + boff);
        }

    const int nwtile = E >> 4;
    const int wstep  = (int)gridDim.x * 4;
    const size_t laneoff = (size_t)l15 * IN_CH + g * 8;

#define LOADSET(F, T) do {                                            \
        const float* xr = x + (size_t)(T) * (16 * IN_CH) + laneoff;   \
        F##0 = *(const floatx4*)(xr);                                 \
        F##1 = *(const floatx4*)(xr + 4);                             \
        F##2 = *(const floatx4*)(xr + 32);                            \
        F##3 = *(const floatx4*)(xr + 36);                            \
    } while (0)

#define COMPUTE(F, T) do {                                            \
        half8 a0, a1;                                                 \
        _Pragma("unroll")                                             \
        for (int j = 0; j < 4; ++j) {                                 \
            a0[j]     = (_Float16)F##0[j];                            \
            a0[j + 4] = (_Float16)F##1[j];                            \
            a1[j]     = (_Float16)F##2[j];                            \
            a1[j + 4] = (_Float16)F##3[j];                            \
        }                                                             \
        floatx4 acc[8];                                               \
        _Pragma("unroll")                                             \
        for (int ct = 0; ct < 8; ++ct) {                              \
            acc[ct][0] = b1v[ct]; acc[ct][1] = b1v[ct];               \
            acc[ct][2] = b1v[ct]; acc[ct][3] = b1v[ct];               \
        }                                                             \
        _Pragma("unroll")                                             \
        for (int ct = 0; ct < 8; ++ct)                                \
            acc[ct] = __builtin_amdgcn_mfma_f32_16x16x32_f16(a0, bfr[0][ct], acc[ct], 0, 0, 0); \
        _Pragma("unroll")                                             \
        for (int ct = 0; ct < 8; ++ct)                                \
            acc[ct] = __builtin_amdgcn_mfma_f32_16x16x32_f16(a1, bfr[1][ct], acc[ct], 0, 0, 0); \
        float s0 = 0.f, s1 = 0.f, s2 = 0.f, s3 = 0.f;                 \
        _Pragma("unroll")                                             \
        for (int ct = 0; ct < 8; ++ct) {                              \
            s0 += fmaxf(acc[ct][0], 0.f) * w2v[ct];                   \
            s1 += fmaxf(acc[ct][1], 0.f) * w2v[ct];                   \
            s2 += fmaxf(acc[ct][2], 0.f) * w2v[ct];                   \
            s3 += fmaxf(acc[ct][3], 0.f) * w2v[ct];                   \
        }                                                             \
        _Pragma("unroll")                                             \
        for (int m = 1; m < 16; m <<= 1) {                            \
            s0 += __shfl_xor(s0, m);                                  \
            s1 += __shfl_xor(s1, m);                                  \
            s2 += __shfl_xor(s2, m);                                  \
            s3 += __shfl_xor(s3, m);                                  \
        }                                                             \
        float v = (l15 == 0) ? s0 : (l15 == 1) ? s1 : (l15 == 2) ? s2 : s3; \
        if (l15 < 4)                                                  \
            score[(T) * 16 + g * 4 + l15] = v + b2v;                  \
    } while (0)

    int wt = blockIdx.x * 4 + wid;
    if (wt < nwtile) {
        floatx4 fA0, fA1, fA2, fA3, fB0, fB1, fB2, fB3;
        LOADSET(fA, wt);
        for (;;) {
            int nxt = wt + wstep;
            bool hn = (nxt < nwtile);
            if (hn) LOADSET(fB, nxt);      // prefetch issued BEFORE compute
            COMPUTE(fA, wt);
            if (!hn) break;
            wt = nxt;
            nxt = wt + wstep;
            hn = (nxt < nwtile);
            if (hn) LOADSET(fA, nxt);
            COMPUTE(fB, wt);
            if (!hn) break;
            wt = nxt;
        }
    }
#undef LOADSET
#undef COMPUTE
}

// ---------------- segment max (run-compressed atomics) ----------------
__global__ __launch_bounds__(256) void seg_max(
    const float* __restrict__ score, const int* __restrict__ batch,
    unsigned* __restrict__ segkey, int E)
{
    int t = blockIdx.x * 256 + threadIdx.x;
    int i0 = t * 8;
    if (i0 + 8 > E) return;
    int4 bA = *(const int4*)(batch + i0);
    int4 bB = *(const int4*)(batch + i0 + 4);
    floatx4 sA = *(const floatx4*)(score + i0);
    floatx4 sB = *(const floatx4*)(score + i0 + 4);
    int   ids[8] = {bA.x, bA.y, bA.z, bA.w, bB.x, bB.y, bB.z, bB.w};
    float ss[8]  = {sA[0], sA[1], sA[2], sA[3], sB[0], sB[1], sB[2], sB[3]};
    int cur = ids[0];
    float m = ss[0];
#pragma unroll
    for (int j = 1; j < 8; ++j) {
        if (ids[j] == cur) {
            m = fmaxf(m, ss[j]);
        } else {
            atomicMax(segkey + cur, fkey(m));
            cur = ids[j];
            m = ss[j];
        }
    }
    atomicMax(segkey + cur, fkey(m));
}

// ---------------- segment denom (run-compressed atomics) ----------------
__global__ __launch_bounds__(256) void seg_denom(
    const float* __restrict__ score, const int* __restrict__ batch,
    const unsigned* __restrict__ segkey, float* __restrict__ denom, int E)
{
    int t = blockIdx.x * 256 + threadIdx.x;
    int i0 = t * 8;
    if (i0 + 8 > E) return;
    int4 bA = *(const int4*)(batch + i0);
    int4 bB = *(const int4*)(batch + i0 + 4);
    floatx4 sA = *(const floatx4*)(score + i0);
    floatx4 sB = *(const floatx4*)(score + i0 + 4);
    int   ids[8] = {bA.x, bA.y, bA.z, bA.w, bB.x, bB.y, bB.z, bB.w};
    float ss[8]  = {sA[0], sA[1], sA[2], sA[3], sB[0], sB[1], sB[2], sB[3]};
    int cur = ids[0];
    float m = funkey(segkey[cur]);
    float a = __expf(ss[0] - m);
#pragma unroll
    for (int j = 1; j < 8; ++j) {
        if (ids[j] == cur) {
            a += __expf(ss[j] - m);
        } else {
            atomicAdd(denom + cur, a);
            cur = ids[j];
            m = funkey(segkey[cur]);
            a = __expf(ss[j] - m);
        }
    }
    atomicAdd(denom + cur, a);
}

// ---------------- finalize: out = exp(s-m)/(denom+eps), in place ----------------
__global__ __launch_bounds__(256) void finalize(
    float* __restrict__ score, const int* __restrict__ batch,
    const unsigned* __restrict__ segkey, const float* __restrict__ denom, int E)
{
    int t = blockIdx.x * 256 + threadIdx.x;
    int i0 = t * 8;
    if (i0 + 8 > E) return;
    int4 bA = *(const int4*)(batch + i0);
    int4 bB = *(const int4*)(batch + i0 + 4);
    floatx4 sA = *(const floatx4*)(score + i0);
    floatx4 sB = *(const floatx4*)(score + i0 + 4);
    int   ids[8] = {bA.x, bA.y, bA.z, bA.w, bB.x, bB.y, bB.z, bB.w};
    float ss[8]  = {sA[0], sA[1], sA[2], sA[3], sB[0], sB[1], sB[2], sB[3]};
    floatx4 oA, oB;
#pragma unroll
    for (int j = 0; j < 4; ++j) {
        float mj = funkey(segkey[ids[j]]);
        oA[j] = __expf(ss[j] - mj) / (denom[ids[j]] + 1e-16f);
    }
#pragma unroll
    for (int j = 0; j < 4; ++j) {
        float mj = funkey(segkey[ids[j + 4]]);
        oB[j] = __expf(ss[j + 4] - mj) / (denom[ids[j + 4]] + 1e-16f);
    }
    *(floatx4*)(score + i0)     = oA;
    *(floatx4*)(score + i0 + 4) = oB;
}

extern "C" void kernel_launch(void* const* d_in, const int* in_sizes, int n_in,
                              void* d_out, int out_size, void* d_ws, size_t ws_size,
                              hipStream_t stream) {
    const float* x   = (const float*)d_in[0];
    const float* w1  = (const float*)d_in[1];
    const float* b1  = (const float*)d_in[2];
    const float* w2  = (const float*)d_in[3];
    const float* b2  = (const float*)d_in[4];
    const int* batch = (const int*)d_in[5];
    float* out = (float*)d_out;
    const int E = in_sizes[5];

    unsigned* segkey = (unsigned*)d_ws;
    float*    denom  = (float*)((char*)d_ws + NSEG * sizeof(unsigned));

    init_seg<<<(NSEG + 255) / 256, 256, 0, stream>>>(segkey, denom);
    // scores are written into d_out (reused as scratch), finalized in place
    mlp_score<<<2048, 256, 0, stream>>>(x, w1, b1, w2, b2, out, E);
    const int nthr = E / 8;
    seg_max   <<<nthr / 256, 256, 0, stream>>>(out, batch, segkey, E);
    seg_denom <<<nthr / 256, 256, 0, stream>>>(out, batch, segkey, denom, E);
    finalize  <<<nthr / 256, 256, 0, stream>>>(out, batch, segkey, denom, E);
}

// Round 4
// 200.042 us; speedup vs baseline: 1.2394x; 1.2394x over previous
//
#include <hip/hip_runtime.h>
#include <hip/hip_bf16.h>
#include <math.h>

typedef _Float16 half8 __attribute__((ext_vector_type(8)));
typedef float    floatx4 __attribute__((ext_vector_type(4)));

#define IN_CH 64
#define HID   128
#define NSEG  4096

__device__ __forceinline__ unsigned fkey(float s) {
    unsigned u = __float_as_uint(s);
    return (u & 0x80000000u) ? ~u : (u | 0x80000000u);
}
__device__ __forceinline__ float funkey(unsigned k) {
    unsigned u = (k & 0x80000000u) ? (k ^ 0x80000000u) : ~k;
    return __uint_as_float(u);
}

// ---------------- init segment scratch ----------------
__global__ void init_seg(unsigned* __restrict__ segkey, float* __restrict__ denom) {
    int i = blockIdx.x * blockDim.x + threadIdx.x;
    if (i < NSEG) { segkey[i] = 0u; denom[i] = 0.0f; }
}

// ---------------- fused MLP -> scores ----------------
// score[e] = relu(x[e,:] @ w1 + b1) @ w2 + b2   via fp16 MFMA (fp32 accum)
// 16 edges/wave/iter. B fragments read from LDS EVERY iter (asm-opaque base
// prevents LICM re-hoisting them into 64 VGPRs). A-tile loads software-
// pipelined one iteration ahead. Target: <=128 VGPR -> 4 waves/SIMD.
__global__ __launch_bounds__(256, 4) void mlp_score(
    const float* __restrict__ x, const float* __restrict__ w1,
    const float* __restrict__ b1, const float* __restrict__ w2,
    const float* __restrict__ b2, float* __restrict__ score, int E)
{
    // w1^T as f16 in LDS: row n (hidden col), 64 k-elements (128B), XOR-swizzled
    // byte(n,k) = n*128 + ((2k) ^ ((n&7)<<4)) -> conflict-free ds_read_b128
    __shared__ unsigned char w1s[HID * 128];

    const int tid = threadIdx.x;
    for (int i = tid; i < IN_CH * HID; i += 256) {
        int k = i >> 7;        // 0..63
        int n = i & 127;       // 0..127
        unsigned byteoff = (unsigned)(n * 128) + (((unsigned)(k * 2)) ^ ((unsigned)(n & 7) << 4));
        *(_Float16*)(w1s + byteoff) = (_Float16)w1[i];
    }

    const int lane = tid & 63;
    const int wid  = tid >> 6;
    const int g    = lane >> 4;   // 0..3
    const int l15  = lane & 15;   // 0..15

    float b1v[8], w2v[8];
#pragma unroll
    for (int t = 0; t < 8; ++t) {
        b1v[t] = b1[t * 16 + l15];
        w2v[t] = w2[t * 16 + l15];
    }
    const float b2v = b2[0];

    __syncthreads();

    // per-lane LDS byte offsets for the two k-steps (row part l15*128 included;
    // ct adds an immediate ct*2048). asm makes them opaque -> ds_reads stay
    // inside the loop instead of being hoisted into 64 registers.
    unsigned bb0 = (unsigned)(l15 * 128) + (((unsigned)(g * 16))      ^ ((unsigned)(l15 & 7) << 4));
    unsigned bb1 = (unsigned)(l15 * 128) + (((unsigned)(64 + g * 16)) ^ ((unsigned)(l15 & 7) << 4));

    const int nwtile = E >> 4;
    const int wstep  = (int)gridDim.x * 4;
    const size_t laneoff = (size_t)l15 * IN_CH + g * 8;

#define LOADSET(F, T) do {                                            \
        const float* xr = x + (size_t)(T) * (16 * IN_CH) + laneoff;   \
        F##0 = *(const floatx4*)(xr);                                 \
        F##1 = *(const floatx4*)(xr + 4);                             \
        F##2 = *(const floatx4*)(xr + 32);                            \
        F##3 = *(const floatx4*)(xr + 36);                            \
    } while (0)

#define COMPUTE(F, T) do {                                            \
        half8 a0, a1;                                                 \
        _Pragma("unroll")                                             \
        for (int j = 0; j < 4; ++j) {                                 \
            a0[j]     = (_Float16)F##0[j];                            \
            a0[j + 4] = (_Float16)F##1[j];                            \
            a1[j]     = (_Float16)F##2[j];                            \
            a1[j + 4] = (_Float16)F##3[j];                            \
        }                                                             \
        unsigned o0 = bb0, o1 = bb1;                                  \
        asm volatile("" : "+v"(o0), "+v"(o1));                        \
        floatx4 acc[8];                                               \
        _Pragma("unroll")                                             \
        for (int ct = 0; ct < 8; ++ct) {                              \
            acc[ct][0] = b1v[ct]; acc[ct][1] = b1v[ct];               \
            acc[ct][2] = b1v[ct]; acc[ct][3] = b1v[ct];               \
        }                                                             \
        _Pragma("unroll")                                             \
        for (int ct = 0; ct < 8; ++ct) {                              \
            half8 bf = *(const half8*)(w1s + o0 + ct * 2048);         \
            acc[ct] = __builtin_amdgcn_mfma_f32_16x16x32_f16(a0, bf, acc[ct], 0, 0, 0); \
        }                                                             \
        _Pragma("unroll")                                             \
        for (int ct = 0; ct < 8; ++ct) {                              \
            half8 bf = *(const half8*)(w1s + o1 + ct * 2048);         \
            acc[ct] = __builtin_amdgcn_mfma_f32_16x16x32_f16(a1, bf, acc[ct], 0, 0, 0); \
        }                                                             \
        float s0 = 0.f, s1 = 0.f, s2 = 0.f, s3 = 0.f;                 \
        _Pragma("unroll")                                             \
        for (int ct = 0; ct < 8; ++ct) {                              \
            s0 += fmaxf(acc[ct][0], 0.f) * w2v[ct];                   \
            s1 += fmaxf(acc[ct][1], 0.f) * w2v[ct];                   \
            s2 += fmaxf(acc[ct][2], 0.f) * w2v[ct];                   \
            s3 += fmaxf(acc[ct][3], 0.f) * w2v[ct];                   \
        }                                                             \
        _Pragma("unroll")                                             \
        for (int m = 1; m < 16; m <<= 1) {                            \
            s0 += __shfl_xor(s0, m);                                  \
            s1 += __shfl_xor(s1, m);                                  \
            s2 += __shfl_xor(s2, m);                                  \
            s3 += __shfl_xor(s3, m);                                  \
        }                                                             \
        float v = (l15 == 0) ? s0 : (l15 == 1) ? s1 : (l15 == 2) ? s2 : s3; \
        if (l15 < 4)                                                  \
            score[(T) * 16 + g * 4 + l15] = v + b2v;                  \
    } while (0)

    int wt = blockIdx.x * 4 + wid;
    if (wt < nwtile) {
        floatx4 fA0, fA1, fA2, fA3, fB0, fB1, fB2, fB3;
        LOADSET(fA, wt);
        for (;;) {
            int nxt = wt + wstep;
            bool hn = (nxt < nwtile);
            if (hn) LOADSET(fB, nxt);      // prefetch issued BEFORE compute
            COMPUTE(fA, wt);
            if (!hn) break;
            wt = nxt;
            nxt = wt + wstep;
            hn = (nxt < nwtile);
            if (hn) LOADSET(fA, nxt);
            COMPUTE(fB, wt);
            if (!hn) break;
            wt = nxt;
        }
    }
#undef LOADSET
#undef COMPUTE
}

// ---------------- segment max (run-compressed atomics) ----------------
__global__ __launch_bounds__(256) void seg_max(
    const float* __restrict__ score, const int* __restrict__ batch,
    unsigned* __restrict__ segkey, int E)
{
    int t = blockIdx.x * 256 + threadIdx.x;
    int i0 = t * 8;
    if (i0 + 8 > E) return;
    int4 bA = *(const int4*)(batch + i0);
    int4 bB = *(const int4*)(batch + i0 + 4);
    floatx4 sA = *(const floatx4*)(score + i0);
    floatx4 sB = *(const floatx4*)(score + i0 + 4);
    int   ids[8] = {bA.x, bA.y, bA.z, bA.w, bB.x, bB.y, bB.z, bB.w};
    float ss[8]  = {sA[0], sA[1], sA[2], sA[3], sB[0], sB[1], sB[2], sB[3]};
    int cur = ids[0];
    float m = ss[0];
#pragma unroll
    for (int j = 1; j < 8; ++j) {
        if (ids[j] == cur) {
            m = fmaxf(m, ss[j]);
        } else {
            atomicMax(segkey + cur, fkey(m));
            cur = ids[j];
            m = ss[j];
        }
    }
    atomicMax(segkey + cur, fkey(m));
}

// ---------------- segment denom (run-compressed atomics) ----------------
__global__ __launch_bounds__(256) void seg_denom(
    const float* __restrict__ score, const int* __restrict__ batch,
    const unsigned* __restrict__ segkey, float* __restrict__ denom, int E)
{
    int t = blockIdx.x * 256 + threadIdx.x;
    int i0 = t * 8;
    if (i0 + 8 > E) return;
    int4 bA = *(const int4*)(batch + i0);
    int4 bB = *(const int4*)(batch + i0 + 4);
    floatx4 sA = *(const floatx4*)(score + i0);
    floatx4 sB = *(const floatx4*)(score + i0 + 4);
    int   ids[8] = {bA.x, bA.y, bA.z, bA.w, bB.x, bB.y, bB.z, bB.w};
    float ss[8]  = {sA[0], sA[1], sA[2], sA[3], sB[0], sB[1], sB[2], sB[3]};
    int cur = ids[0];
    float m = funkey(segkey[cur]);
    float a = __expf(ss[0] - m);
#pragma unroll
    for (int j = 1; j < 8; ++j) {
        if (ids[j] == cur) {
            a += __expf(ss[j] - m);
        } else {
            atomicAdd(denom + cur, a);
            cur = ids[j];
            m = funkey(segkey[cur]);
            a = __expf(ss[j] - m);
        }
    }
    atomicAdd(denom + cur, a);
}

// ---------------- finalize: out = exp(s-m)/(denom+eps), in place ----------------
__global__ __launch_bounds__(256) void finalize(
    float* __restrict__ score, const int* __restrict__ batch,
    const unsigned* __restrict__ segkey, const float* __restrict__ denom, int E)
{
    int t = blockIdx.x * 256 + threadIdx.x;
    int i0 = t * 8;
    if (i0 + 8 > E) return;
    int4 bA = *(const int4*)(batch + i0);
    int4 bB = *(const int4*)(batch + i0 + 4);
    floatx4 sA = *(const floatx4*)(score + i0);
    floatx4 sB = *(const floatx4*)(score + i0 + 4);
    int   ids[8] = {bA.x, bA.y, bA.z, bA.w, bB.x, bB.y, bB.z, bB.w};
    float ss[8]  = {sA[0], sA[1], sA[2], sA[3], sB[0], sB[1], sB[2], sB[3]};
    floatx4 oA, oB;
#pragma unroll
    for (int j = 0; j < 4; ++j) {
        float mj = funkey(segkey[ids[j]]);
        oA[j] = __expf(ss[j] - mj) / (denom[ids[j]] + 1e-16f);
    }
#pragma unroll
    for (int j = 0; j < 4; ++j) {
        float mj = funkey(segkey[ids[j + 4]]);
        oB[j] = __expf(ss[j + 4] - mj) / (denom[ids[j + 4]] + 1e-16f);
    }
    *(floatx4*)(score + i0)     = oA;
    *(floatx4*)(score + i0 + 4) = oB;
}

extern "C" void kernel_launch(void* const* d_in, const int* in_sizes, int n_in,
                              void* d_out, int out_size, void* d_ws, size_t ws_size,
                              hipStream_t stream) {
    const float* x   = (const float*)d_in[0];
    const float* w1  = (const float*)d_in[1];
    const float* b1  = (const float*)d_in[2];
    const float* w2  = (const float*)d_in[3];
    const float* b2  = (const float*)d_in[4];
    const int* batch = (const int*)d_in[5];
    float* out = (float*)d_out;
    const int E = in_sizes[5];

    unsigned* segkey = (unsigned*)d_ws;
    float*    denom  = (float*)((char*)d_ws + NSEG * sizeof(unsigned));

    init_seg<<<(NSEG + 255) / 256, 256, 0, stream>>>(segkey, denom);
    // scores are written into d_out (reused as scratch), finalized in place
    mlp_score<<<1024, 256, 0, stream>>>(x, w1, b1, w2, b2, out, E);
    const int nthr = E / 8;
    seg_max   <<<nthr / 256, 256, 0, stream>>>(out, batch, segkey, E);
    seg_denom <<<nthr / 256, 256, 0, stream>>>(out, batch, segkey, denom, E);
    finalize  <<<nthr / 256, 256, 0, stream>>>(out, batch, segkey, denom, E);
}

// Round 6
// 191.473 us; speedup vs baseline: 1.2949x; 1.0448x over previous
//
#include <hip/hip_runtime.h>
#include <hip/hip_bf16.h>
#include <math.h>

typedef _Float16 half8  __attribute__((ext_vector_type(8)));
typedef __fp16   fp16x2 __attribute__((ext_vector_type(2)));
typedef float    floatx4 __attribute__((ext_vector_type(4)));

#define IN_CH 64
#define HID   128
#define NSEG  4096

__device__ __forceinline__ unsigned fkey(float s) {
    unsigned u = __float_as_uint(s);
    return (u & 0x80000000u) ? ~u : (u | 0x80000000u);
}
__device__ __forceinline__ float funkey(unsigned k) {
    unsigned u = (k & 0x80000000u) ? (k ^ 0x80000000u) : ~k;
    return __uint_as_float(u);
}

// ---------------- init segment scratch ----------------
__global__ void init_seg(unsigned* __restrict__ segkey, float* __restrict__ denom) {
    int i = blockIdx.x * blockDim.x + threadIdx.x;
    if (i < NSEG) { segkey[i] = 0u; denom[i] = 0.0f; }
}

// ---------------- fused MLP -> scores (swapped-operand MFMA) ----------------
// h^T = w1^T (A, reg-resident) @ x^T (B).  D: col=lane&15 -> lane owns ONE edge;
// row=g*4+reg -> 32 hidden units per lane.  Layer-2 dot is lane-local; only a
// 2-stage xor-shuffle over the 4 g-groups. Bias b1 folded into MFMA C operand.
__global__ __launch_bounds__(256, 2) void mlp_score(
    const float* __restrict__ x, const float* __restrict__ w1,
    const float* __restrict__ b1, const float* __restrict__ w2,
    const float* __restrict__ b2, float* __restrict__ score, int E)
{
    const int tid  = threadIdx.x;
    const int lane = tid & 63;
    const int wid  = tid >> 6;
    const int g    = lane >> 4;   // 0..3
    const int l15  = lane & 15;   // 0..15

    // ---- one-time: w1 A-fragments (16 frags = 64 VGPRs), RTN cvt
    // afr[ks][ct], element j = w1[ch = ks*32 + g*8 + j][hid = ct*16 + l15]
    half8 afr[2][8];
#pragma unroll
    for (int ks = 0; ks < 2; ++ks)
#pragma unroll
        for (int ct = 0; ct < 8; ++ct) {
            const float* wp = w1 + (size_t)(ks * 32 + g * 8) * HID + ct * 16 + l15;
            half8 h;
#pragma unroll
            for (int j = 0; j < 8; ++j) h[j] = (_Float16)wp[(size_t)j * HID];
            afr[ks][ct] = h;
        }

    // ---- one-time: bias-as-C fragments and w2 fragments (32+32 VGPRs)
    // C/D row = g*4 + reg  -> value index ct*16 + g*4 + reg (same for all l15)
    floatx4 biasC[8], w2r[8];
#pragma unroll
    for (int ct = 0; ct < 8; ++ct)
#pragma unroll
        for (int r = 0; r < 4; ++r) {
            biasC[ct][r] = b1[ct * 16 + g * 4 + r];
            w2r[ct][r]   = w2[ct * 16 + g * 4 + r];
        }
    const float b2v = b2[0];

    const int nwtile = E >> 4;                 // 16 edges per wave-tile
    const int wstep  = (int)gridDim.x * 4;
    const size_t laneoff = (size_t)l15 * IN_CH + g * 8;

#define LOADSET(F, T) do {                                            \
        const float* xr = x + (size_t)(T) * (16 * IN_CH) + laneoff;   \
        F##0 = *(const floatx4*)(xr);                                 \
        F##1 = *(const floatx4*)(xr + 4);                             \
        F##2 = *(const floatx4*)(xr + 32);                            \
        F##3 = *(const floatx4*)(xr + 36);                            \
    } while (0)

    union H8 { half8 h8; fp16x2 h2[4]; };

#define COMPUTE(F, T) do {                                            \
        H8 ub, uc;                                                    \
        ub.h2[0] = __builtin_amdgcn_cvt_pkrtz(F##0[0], F##0[1]);      \
        ub.h2[1] = __builtin_amdgcn_cvt_pkrtz(F##0[2], F##0[3]);      \
        ub.h2[2] = __builtin_amdgcn_cvt_pkrtz(F##1[0], F##1[1]);      \
        ub.h2[3] = __builtin_amdgcn_cvt_pkrtz(F##1[2], F##1[3]);      \
        uc.h2[0] = __builtin_amdgcn_cvt_pkrtz(F##2[0], F##2[1]);      \
        uc.h2[1] = __builtin_amdgcn_cvt_pkrtz(F##2[2], F##2[3]);      \
        uc.h2[2] = __builtin_amdgcn_cvt_pkrtz(F##3[0], F##3[1]);      \
        uc.h2[3] = __builtin_amdgcn_cvt_pkrtz(F##3[2], F##3[3]);      \
        floatx4 acc[8];                                               \
        _Pragma("unroll")                                             \
        for (int ct = 0; ct < 8; ++ct)                                \
            acc[ct] = __builtin_amdgcn_mfma_f32_16x16x32_f16(afr[0][ct], ub.h8, biasC[ct], 0, 0, 0); \
        _Pragma("unroll")                                             \
        for (int ct = 0; ct < 8; ++ct)                                \
            acc[ct] = __builtin_amdgcn_mfma_f32_16x16x32_f16(afr[1][ct], uc.h8, acc[ct], 0, 0, 0);   \
        float s0 = 0.f, s1 = 0.f, s2 = 0.f, s3 = 0.f;                 \
        _Pragma("unroll")                                             \
        for (int ct = 0; ct < 8; ++ct) {                              \
            s0 += fmaxf(acc[ct][0], 0.f) * w2r[ct][0];                \
            s1 += fmaxf(acc[ct][1], 0.f) * w2r[ct][1];                \
            s2 += fmaxf(acc[ct][2], 0.f) * w2r[ct][2];                \
            s3 += fmaxf(acc[ct][3], 0.f) * w2r[ct][3];                \
        }                                                             \
        float s = (s0 + s1) + (s2 + s3);                              \
        s += __shfl_xor(s, 16);                                       \
        s += __shfl_xor(s, 32);                                       \
        if (lane < 16)                                                \
            score[(T) * 16 + l15] = s + b2v;                          \
    } while (0)

    int wt = blockIdx.x * 4 + wid;
    if (wt < nwtile) {
        floatx4 fA0, fA1, fA2, fA3, fB0, fB1, fB2, fB3;
        LOADSET(fA, wt);
        for (;;) {
            int nxt = wt + wstep;
            bool hn = (nxt < nwtile);
            if (hn) LOADSET(fB, nxt);      // prefetch issued BEFORE compute
            COMPUTE(fA, wt);
            if (!hn) break;
            wt = nxt;
            nxt = wt + wstep;
            hn = (nxt < nwtile);
            if (hn) LOADSET(fA, nxt);
            COMPUTE(fB, wt);
            if (!hn) break;
            wt = nxt;
        }
    }
#undef LOADSET
#undef COMPUTE
}

// ---------------- segment max (run-compressed atomics) ----------------
__global__ __launch_bounds__(256) void seg_max(
    const float* __restrict__ score, const int* __restrict__ batch,
    unsigned* __restrict__ segkey, int E)
{
    int t = blockIdx.x * 256 + threadIdx.x;
    int i0 = t * 8;
    if (i0 + 8 > E) return;
    int4 bA = *(const int4*)(batch + i0);
    int4 bB = *(const int4*)(batch + i0 + 4);
    floatx4 sA = *(const floatx4*)(score + i0);
    floatx4 sB = *(const floatx4*)(score + i0 + 4);
    int   ids[8] = {bA.x, bA.y, bA.z, bA.w, bB.x, bB.y, bB.z, bB.w};
    float ss[8]  = {sA[0], sA[1], sA[2], sA[3], sB[0], sB[1], sB[2], sB[3]};
    int cur = ids[0];
    float m = ss[0];
#pragma unroll
    for (int j = 1; j < 8; ++j) {
        if (ids[j] == cur) {
            m = fmaxf(m, ss[j]);
        } else {
            atomicMax(segkey + cur, fkey(m));
            cur = ids[j];
            m = ss[j];
        }
    }
    atomicMax(segkey + cur, fkey(m));
}

// ---------------- segment denom (run-compressed atomics) ----------------
__global__ __launch_bounds__(256) void seg_denom(
    const float* __restrict__ score, const int* __restrict__ batch,
    const unsigned* __restrict__ segkey, float* __restrict__ denom, int E)
{
    int t = blockIdx.x * 256 + threadIdx.x;
    int i0 = t * 8;
    if (i0 + 8 > E) return;
    int4 bA = *(const int4*)(batch + i0);
    int4 bB = *(const int4*)(batch + i0 + 4);
    floatx4 sA = *(const floatx4*)(score + i0);
    floatx4 sB = *(const floatx4*)(score + i0 + 4);
    int   ids[8] = {bA.x, bA.y, bA.z, bA.w, bB.x, bB.y, bB.z, bB.w};
    float ss[8]  = {sA[0], sA[1], sA[2], sA[3], sB[0], sB[1], sB[2], sB[3]};
    int cur = ids[0];
    float m = funkey(segkey[cur]);
    float a = __expf(ss[0] - m);
#pragma unroll
    for (int j = 1; j < 8; ++j) {
        if (ids[j] == cur) {
            a += __expf(ss[j] - m);
        } else {
            atomicAdd(denom + cur, a);
            cur = ids[j];
            m = funkey(segkey[cur]);
            a = __expf(ss[j] - m);
        }
    }
    atomicAdd(denom + cur, a);
}

// ---------------- finalize: out = exp(s-m)/(denom+eps), in place ----------------
__global__ __launch_bounds__(256) void finalize(
    float* __restrict__ score, const int* __restrict__ batch,
    const unsigned* __restrict__ segkey, const float* __restrict__ denom, int E)
{
    int t = blockIdx.x * 256 + threadIdx.x;
    int i0 = t * 8;
    if (i0 + 8 > E) return;
    int4 bA = *(const int4*)(batch + i0);
    int4 bB = *(const int4*)(batch + i0 + 4);
    floatx4 sA = *(const floatx4*)(score + i0);
    floatx4 sB = *(const floatx4*)(score + i0 + 4);
    int   ids[8] = {bA.x, bA.y, bA.z, bA.w, bB.x, bB.y, bB.z, bB.w};
    float ss[8]  = {sA[0], sA[1], sA[2], sA[3], sB[0], sB[1], sB[2], sB[3]};
    floatx4 oA, oB;
#pragma unroll
    for (int j = 0; j < 4; ++j) {
        float mj = funkey(segkey[ids[j]]);
        oA[j] = __expf(ss[j] - mj) / (denom[ids[j]] + 1e-16f);
    }
#pragma unroll
    for (int j = 0; j < 4; ++j) {
        float mj = funkey(segkey[ids[j + 4]]);
        oB[j] = __expf(ss[j + 4] - mj) / (denom[ids[j + 4]] + 1e-16f);
    }
    *(floatx4*)(score + i0)     = oA;
    *(floatx4*)(score + i0 + 4) = oB;
}

extern "C" void kernel_launch(void* const* d_in, const int* in_sizes, int n_in,
                              void* d_out, int out_size, void* d_ws, size_t ws_size,
                              hipStream_t stream) {
    const float* x   = (const float*)d_in[0];
    const float* w1  = (const float*)d_in[1];
    const float* b1  = (const float*)d_in[2];
    const float* w2  = (const float*)d_in[3];
    const float* b2  = (const float*)d_in[4];
    const int* batch = (const int*)d_in[5];
    float* out = (float*)d_out;
    const int E = in_sizes[5];

    unsigned* segkey = (unsigned*)d_ws;
    float*    denom  = (float*)((char*)d_ws + NSEG * sizeof(unsigned));

    init_seg<<<(NSEG + 255) / 256, 256, 0, stream>>>(segkey, denom);
    // scores are written into d_out (reused as scratch), finalized in place
    mlp_score<<<1024, 256, 0, stream>>>(x, w1, b1, w2, b2, out, E);
    const int nthr = E / 8;
    seg_max   <<<nthr / 256, 256, 0, stream>>>(out, batch, segkey, E);
    seg_denom <<<nthr / 256, 256, 0, stream>>>(out, batch, segkey, denom, E);
    finalize  <<<nthr / 256, 256, 0, stream>>>(out, batch, segkey, denom, E);
}